// Round 8
// baseline (255.999 us; speedup 1.0000x reference)
//
#include <hip/hip_runtime.h>
#include <hip/hip_bf16.h>

// out[e] = tanh(prop[idx_i[e]] @ wi1) @ wi2 + tanh(prop[idx_j[e]] @ wj1) @ wj2
// Factored: F_I = mlp(prop, wi*), F_J = mlp(prop, wj*)  [per-node, 16x fewer FLOPs]
//           out[e] = F_I[idx_i[e]] + F_J[idx_j[e]]      [gather-add]
//
// History: R4 bf16 flat tables = 202 us (best). R5 L3-phasing REGRESSED (223).
//          R6 XCD/L2-sharding REGRESSED (247; sharded stores broke the write
//          stream's line contiguity). Lesson: table reads go to HBM no matter
//          what; never degrade the 410 MB write stream's contiguity.
// R7: revert to R4 layout; 4-DEEP SOFTWARE-PIPELINED gather (8 table loads in
//     flight per thread) to close the ~35 us latency-hiding gap
//     (180 us observed vs ~146 us mixed-BW floor).

typedef __attribute__((ext_vector_type(8))) short bf16x8;   // 8 bf16 (4 VGPRs)
typedef __attribute__((ext_vector_type(4))) float f32x4;    // MFMA accumulator / 16B vec

__device__ __forceinline__ unsigned short f2bf(float f) {
    // round-to-nearest-even fp32 -> bf16 (inputs are normal floats)
    unsigned int u = __float_as_uint(f);
    unsigned int r = (u + 0x7fffu + ((u >> 16) & 1u)) >> 16;
    return (unsigned short)r;
}
__device__ __forceinline__ float bf2f(short b) {
    return __uint_as_float((unsigned int)(unsigned short)b << 16);
}

#define LDK 136  // padded LDS row stride in bf16 elems: 272 B (16B-aligned reads)

// Core: tanh(src[map(row)] @ W1) @ W2, 64 rows/block, 4 waves x 16 rows.
// BF16OUT: write bf16 table [row][128]. Else fp32 [row][128] with opt. accumulate.
template <bool BF16OUT>
__device__ __forceinline__ void mlp_block(
    const float* __restrict__ src, const int* __restrict__ idx,
    const float* __restrict__ W1, const float* __restrict__ W2,
    float* __restrict__ dstf, unsigned short* __restrict__ dstb,
    int n_rows, int accumulate, int bid)
{
    __shared__ short Wt[128][LDK];      // W^T as bf16 bits: Wt[n][k] = W[k][n]
    __shared__ short Tl[4][16][LDK];    // per-wave tanh(h) tile (A-operand for GEMM2)

    const int tid  = threadIdx.x;
    const int lane = tid & 63;
    const int wave = tid >> 6;
    const int lo   = lane & 15;   // col within 16-tile / A row
    const int q    = lane >> 4;   // k-group (A/B) / row-group (C/D)
    const int r0   = bid * 64;

    // ---- stage W1^T into LDS (coalesced global read, ds_write_b64) ----
    {
        const int n  = tid & 127;
        const int kq = (tid >> 7) * 4;
        for (int k0 = kq; k0 < 128; k0 += 8) {
            ushort4 p;
            p.x = f2bf(W1[(k0 + 0) * 128 + n]);
            p.y = f2bf(W1[(k0 + 1) * 128 + n]);
            p.z = f2bf(W1[(k0 + 2) * 128 + n]);
            p.w = f2bf(W1[(k0 + 3) * 128 + n]);
            *reinterpret_cast<ushort4*>(&Wt[n][k0]) = p;
        }
    }
    __syncthreads();

    // ---- A fragments: 16 rows per wave, row = lane&15, k = (lane>>4)*8 + i ----
    int arow   = r0 + wave * 16 + lo;
    int arow_c = arow < n_rows ? arow : n_rows - 1;
    int srow   = idx ? idx[arow_c] : arow_c;
    const float4* ap = reinterpret_cast<const float4*>(src + (size_t)srow * 128);

    bf16x8 afr[4];
    #pragma unroll
    for (int kk = 0; kk < 4; ++kk) {
        float4 p0 = ap[kk * 8 + q * 2 + 0];
        float4 p1 = ap[kk * 8 + q * 2 + 1];
        afr[kk][0] = (short)f2bf(p0.x); afr[kk][1] = (short)f2bf(p0.y);
        afr[kk][2] = (short)f2bf(p0.z); afr[kk][3] = (short)f2bf(p0.w);
        afr[kk][4] = (short)f2bf(p1.x); afr[kk][5] = (short)f2bf(p1.y);
        afr[kk][6] = (short)f2bf(p1.z); afr[kk][7] = (short)f2bf(p1.w);
    }

    // ---- GEMM1: h = A @ W1 ----
    f32x4 acc[8];
    #pragma unroll
    for (int nb = 0; nb < 8; ++nb) acc[nb] = f32x4{0.f, 0.f, 0.f, 0.f};
    #pragma unroll
    for (int nb = 0; nb < 8; ++nb) {
        const int col = nb * 16 + lo;
        #pragma unroll
        for (int kk = 0; kk < 4; ++kk) {
            bf16x8 b = *reinterpret_cast<const bf16x8*>(&Wt[col][kk * 32 + q * 8]);
            acc[nb] = __builtin_amdgcn_mfma_f32_16x16x32_bf16(afr[kk], b, acc[nb], 0, 0, 0);
        }
    }

    __syncthreads();  // all waves done reading W1^T before overwrite

    // ---- stage W2^T (reuse Wt) ----
    {
        const int n  = tid & 127;
        const int kq = (tid >> 7) * 4;
        for (int k0 = kq; k0 < 128; k0 += 8) {
            ushort4 p;
            p.x = f2bf(W2[(k0 + 0) * 128 + n]);
            p.y = f2bf(W2[(k0 + 1) * 128 + n]);
            p.z = f2bf(W2[(k0 + 2) * 128 + n]);
            p.w = f2bf(W2[(k0 + 3) * 128 + n]);
            *reinterpret_cast<ushort4*>(&Wt[n][k0]) = p;
        }
    }
    // ---- tanh, C/D layout (col=lane&15, row=(lane>>4)*4+r) -> Tl row-major ----
    #pragma unroll
    for (int nb = 0; nb < 8; ++nb) {
        #pragma unroll
        for (int r = 0; r < 4; ++r) {
            Tl[wave][q * 4 + r][nb * 16 + lo] = (short)f2bf(tanhf(acc[nb][r]));
        }
    }
    __syncthreads();

    // ---- A2 fragments from tanh tile (row = lane&15, k-contiguous) ----
    bf16x8 a2[4];
    #pragma unroll
    for (int kk = 0; kk < 4; ++kk)
        a2[kk] = *reinterpret_cast<const bf16x8*>(&Tl[wave][lo][kk * 32 + q * 8]);

    // ---- GEMM2: y = tanh(h) @ W2 ----
    f32x4 acc2[8];
    #pragma unroll
    for (int nb = 0; nb < 8; ++nb) acc2[nb] = f32x4{0.f, 0.f, 0.f, 0.f};
    #pragma unroll
    for (int nb = 0; nb < 8; ++nb) {
        const int col = nb * 16 + lo;
        #pragma unroll
        for (int kk = 0; kk < 4; ++kk) {
            bf16x8 b = *reinterpret_cast<const bf16x8*>(&Wt[col][kk * 32 + q * 8]);
            acc2[nb] = __builtin_amdgcn_mfma_f32_16x16x32_bf16(a2[kk], b, acc2[nb], 0, 0, 0);
        }
    }

    // ---- store (C/D layout: col=nb*16+lo, row=r0+wave*16+q*4+r) ----
    #pragma unroll
    for (int r = 0; r < 4; ++r) {
        int row = r0 + wave * 16 + q * 4 + r;
        if (row < n_rows) {
            #pragma unroll
            for (int nb = 0; nb < 8; ++nb) {
                int c = nb * 16 + lo;
                if (BF16OUT) {
                    dstb[(size_t)row * 128 + c] = f2bf(acc2[nb][r]);
                } else {
                    float* drow = dstf + (size_t)row * 128;
                    if (accumulate) drow[c] += acc2[nb][r];
                    else            drow[c]  = acc2[nb][r];
                }
            }
        }
    }
}

// Merged per-node MLPs -> bf16 tables: blocks [0,nblk) -> FI; [nblk,2*nblk) -> FJ.
__global__ __launch_bounds__(256) void mlp2_kernel(
    const float* __restrict__ src,
    const float* __restrict__ w11, const float* __restrict__ w12,
    const float* __restrict__ w21, const float* __restrict__ w22,
    unsigned short* __restrict__ FI, unsigned short* __restrict__ FJ,
    int n_rows, int nblk)
{
    const bool second = (int)blockIdx.x >= nblk;
    mlp_block<true>(src, nullptr,
                    second ? w21 : w11, second ? w22 : w12,
                    nullptr, second ? FJ : FI, n_rows, 0,
                    second ? (int)blockIdx.x - nblk : (int)blockIdx.x);
}

// Fallback per-edge MLP (workspace too small), fp32 accumulate into out.
__global__ __launch_bounds__(256) void mlp_kernel(
    const float* __restrict__ src, const int* __restrict__ idx,
    const float* __restrict__ W1, const float* __restrict__ W2,
    float* __restrict__ dst, int n_rows, int accumulate)
{
    mlp_block<false>(src, idx, W1, W2, dst, nullptr, n_rows, accumulate,
                     (int)blockIdx.x);
}

// Gather-add, 4-deep software pipeline. t = (edge<<4) | chunk; each t handles
// 8 bf16 cols -> 32 B of fp32 output. Per unrolled step: 8 idx loads issued,
// then 8 table loads in flight, then 4x convert + 2 NT stores. Wave-level:
// 16 lanes/edge read the full 256 B table row; 64 consecutive t per wave
// NT-store 2 KB contiguous (line-perfect write stream).
__global__ __launch_bounds__(256) void gather_add_kernel(
    const unsigned short* __restrict__ FI, const unsigned short* __restrict__ FJ,
    const int* __restrict__ idx_i, const int* __restrict__ idx_j,
    float* __restrict__ out, int n_edges)
{
    const int total  = n_edges * 16;
    const int stride = gridDim.x * 256;
    int t = blockIdx.x * 256 + threadIdx.x;

    for (; t + 3 * stride < total; t += 4 * stride) {
        int ni[4], nj[4], qq[4];
        #pragma unroll
        for (int u = 0; u < 4; ++u) {
            const int tu = t + u * stride;
            const int e  = tu >> 4;
            qq[u] = tu & 15;
            ni[u] = idx_i[e];
            nj[u] = idx_j[e];
        }
        bf16x8 a[4], b[4];
        #pragma unroll
        for (int u = 0; u < 4; ++u) {
            a[u] = *reinterpret_cast<const bf16x8*>(&FI[(size_t)ni[u] * 128 + qq[u] * 8]);
            b[u] = *reinterpret_cast<const bf16x8*>(&FJ[(size_t)nj[u] * 128 + qq[u] * 8]);
        }
        #pragma unroll
        for (int u = 0; u < 4; ++u) {
            const int tu = t + u * stride;
            f32x4 lo, hi;
            #pragma unroll
            for (int k = 0; k < 4; ++k) {
                lo[k] = bf2f(a[u][k])     + bf2f(b[u][k]);
                hi[k] = bf2f(a[u][k + 4]) + bf2f(b[u][k + 4]);
            }
            f32x4* op = reinterpret_cast<f32x4*>(&out[(size_t)tu * 8]);
            __builtin_nontemporal_store(lo, op);
            __builtin_nontemporal_store(hi, op + 1);
        }
    }
    // tail
    for (; t < total; t += stride) {
        const int e  = t >> 4;
        const int qq = t & 15;
        const int ni = idx_i[e];
        const int nj = idx_j[e];
        bf16x8 a = *reinterpret_cast<const bf16x8*>(&FI[(size_t)ni * 128 + qq * 8]);
        bf16x8 b = *reinterpret_cast<const bf16x8*>(&FJ[(size_t)nj * 128 + qq * 8]);
        f32x4 lo, hi;
        #pragma unroll
        for (int k = 0; k < 4; ++k) {
            lo[k] = bf2f(a[k])     + bf2f(b[k]);
            hi[k] = bf2f(a[k + 4]) + bf2f(b[k + 4]);
        }
        f32x4* op = reinterpret_cast<f32x4*>(&out[(size_t)t * 8]);
        __builtin_nontemporal_store(lo, op);
        __builtin_nontemporal_store(hi, op + 1);
    }
}

extern "C" void kernel_launch(void* const* d_in, const int* in_sizes, int n_in,
                              void* d_out, int out_size, void* d_ws, size_t ws_size,
                              hipStream_t stream)
{
    const float* prop  = (const float*)d_in[0];
    const int*   idx_i = (const int*)d_in[1];
    const int*   idx_j = (const int*)d_in[2];
    const float* wi1   = (const float*)d_in[3];
    const float* wi2   = (const float*)d_in[4];
    const float* wj1   = (const float*)d_in[5];
    const float* wj2   = (const float*)d_in[6];
    float* out = (float*)d_out;

    const int n_nodes = in_sizes[0] / 128;
    const int n_edges = in_sizes[1];

    const size_t f_elems = (size_t)n_nodes * 128;
    const size_t need    = 2 * f_elems * sizeof(unsigned short);

    if (ws_size >= need) {
        // Fast path: per-node MLPs into bf16 tables (one dispatch), then gather-add.
        unsigned short* FI = (unsigned short*)d_ws;
        unsigned short* FJ = FI + f_elems;
        int nblk = (n_nodes + 63) / 64;
        mlp2_kernel<<<2 * nblk, 256, 0, stream>>>(prop, wi1, wi2, wj1, wj2,
                                                  FI, FJ, n_nodes, nblk);

        // 2048 blocks = 8 blocks/CU, fully co-resident; grid-stride, 4-deep pipeline.
        gather_add_kernel<<<2048, 256, 0, stream>>>(FI, FJ, idx_i, idx_j,
                                                    out, n_edges);
    } else {
        // Fallback (workspace too small): per-edge MLP with gather, then accumulate pass.
        int nblk = (n_edges + 63) / 64;
        mlp_kernel<<<nblk, 256, 0, stream>>>(prop, idx_i, wi1, wi2, out, n_edges, 0);
        mlp_kernel<<<nblk, 256, 0, stream>>>(prop, idx_j, wj1, wj2, out, n_edges, 1);
    }
}

// Round 9
// 206.642 us; speedup vs baseline: 1.2389x; 1.2389x over previous
//
#include <hip/hip_runtime.h>
#include <hip/hip_bf16.h>

// out[e] = tanh(prop[idx_i[e]] @ wi1) @ wi2 + tanh(prop[idx_j[e]] @ wj1) @ wj2
// Factored: F_I = mlp(prop, wi*), F_J = mlp(prop, wj*)  [per-node, 16x fewer FLOPs]
//           out[e] = F_I[idx_i[e]] + F_J[idx_j[e]]      [gather-add]
//
// History: R4 bf16 flat tables = 202 us (BEST). R5 L3-phasing 223. R6 L2-shard
//          247 (broke write-line contiguity). R7 strided 4-unroll 256 (each
//          wave cycled 4 store regions 16 MB apart -> DRAM page thrash).
// LAW (3x confirmed): the 410 MB NT write stream must stay sequential per
//          wave/block; table reads go to HBM regardless of cache tricks.
// R8: R7's read pipelining re-done with CONTIGUOUS addressing: each block owns
//     a 1024-elem super-chunk (32 KB contiguous output), unrolled 4x256 ->
//     8 table loads in flight per thread, write stream byte-identical to R4.

typedef __attribute__((ext_vector_type(8))) short bf16x8;   // 8 bf16 (4 VGPRs)
typedef __attribute__((ext_vector_type(4))) float f32x4;    // MFMA accumulator / 16B vec

__device__ __forceinline__ unsigned short f2bf(float f) {
    // round-to-nearest-even fp32 -> bf16 (inputs are normal floats)
    unsigned int u = __float_as_uint(f);
    unsigned int r = (u + 0x7fffu + ((u >> 16) & 1u)) >> 16;
    return (unsigned short)r;
}
__device__ __forceinline__ float bf2f(short b) {
    return __uint_as_float((unsigned int)(unsigned short)b << 16);
}

#define LDK 136  // padded LDS row stride in bf16 elems: 272 B (16B-aligned reads)

// Core: tanh(src[map(row)] @ W1) @ W2, 64 rows/block, 4 waves x 16 rows.
// BF16OUT: write bf16 table [row][128]. Else fp32 [row][128] with opt. accumulate.
template <bool BF16OUT>
__device__ __forceinline__ void mlp_block(
    const float* __restrict__ src, const int* __restrict__ idx,
    const float* __restrict__ W1, const float* __restrict__ W2,
    float* __restrict__ dstf, unsigned short* __restrict__ dstb,
    int n_rows, int accumulate, int bid)
{
    __shared__ short Wt[128][LDK];      // W^T as bf16 bits: Wt[n][k] = W[k][n]
    __shared__ short Tl[4][16][LDK];    // per-wave tanh(h) tile (A-operand for GEMM2)

    const int tid  = threadIdx.x;
    const int lane = tid & 63;
    const int wave = tid >> 6;
    const int lo   = lane & 15;   // col within 16-tile / A row
    const int q    = lane >> 4;   // k-group (A/B) / row-group (C/D)
    const int r0   = bid * 64;

    // ---- stage W1^T into LDS (coalesced global read, ds_write_b64) ----
    {
        const int n  = tid & 127;
        const int kq = (tid >> 7) * 4;
        for (int k0 = kq; k0 < 128; k0 += 8) {
            ushort4 p;
            p.x = f2bf(W1[(k0 + 0) * 128 + n]);
            p.y = f2bf(W1[(k0 + 1) * 128 + n]);
            p.z = f2bf(W1[(k0 + 2) * 128 + n]);
            p.w = f2bf(W1[(k0 + 3) * 128 + n]);
            *reinterpret_cast<ushort4*>(&Wt[n][k0]) = p;
        }
    }
    __syncthreads();

    // ---- A fragments: 16 rows per wave, row = lane&15, k = (lane>>4)*8 + i ----
    int arow   = r0 + wave * 16 + lo;
    int arow_c = arow < n_rows ? arow : n_rows - 1;
    int srow   = idx ? idx[arow_c] : arow_c;
    const float4* ap = reinterpret_cast<const float4*>(src + (size_t)srow * 128);

    bf16x8 afr[4];
    #pragma unroll
    for (int kk = 0; kk < 4; ++kk) {
        float4 p0 = ap[kk * 8 + q * 2 + 0];
        float4 p1 = ap[kk * 8 + q * 2 + 1];
        afr[kk][0] = (short)f2bf(p0.x); afr[kk][1] = (short)f2bf(p0.y);
        afr[kk][2] = (short)f2bf(p0.z); afr[kk][3] = (short)f2bf(p0.w);
        afr[kk][4] = (short)f2bf(p1.x); afr[kk][5] = (short)f2bf(p1.y);
        afr[kk][6] = (short)f2bf(p1.z); afr[kk][7] = (short)f2bf(p1.w);
    }

    // ---- GEMM1: h = A @ W1 ----
    f32x4 acc[8];
    #pragma unroll
    for (int nb = 0; nb < 8; ++nb) acc[nb] = f32x4{0.f, 0.f, 0.f, 0.f};
    #pragma unroll
    for (int nb = 0; nb < 8; ++nb) {
        const int col = nb * 16 + lo;
        #pragma unroll
        for (int kk = 0; kk < 4; ++kk) {
            bf16x8 b = *reinterpret_cast<const bf16x8*>(&Wt[col][kk * 32 + q * 8]);
            acc[nb] = __builtin_amdgcn_mfma_f32_16x16x32_bf16(afr[kk], b, acc[nb], 0, 0, 0);
        }
    }

    __syncthreads();  // all waves done reading W1^T before overwrite

    // ---- stage W2^T (reuse Wt) ----
    {
        const int n  = tid & 127;
        const int kq = (tid >> 7) * 4;
        for (int k0 = kq; k0 < 128; k0 += 8) {
            ushort4 p;
            p.x = f2bf(W2[(k0 + 0) * 128 + n]);
            p.y = f2bf(W2[(k0 + 1) * 128 + n]);
            p.z = f2bf(W2[(k0 + 2) * 128 + n]);
            p.w = f2bf(W2[(k0 + 3) * 128 + n]);
            *reinterpret_cast<ushort4*>(&Wt[n][k0]) = p;
        }
    }
    // ---- tanh, C/D layout (col=lane&15, row=(lane>>4)*4+r) -> Tl row-major ----
    #pragma unroll
    for (int nb = 0; nb < 8; ++nb) {
        #pragma unroll
        for (int r = 0; r < 4; ++r) {
            Tl[wave][q * 4 + r][nb * 16 + lo] = (short)f2bf(tanhf(acc[nb][r]));
        }
    }
    __syncthreads();

    // ---- A2 fragments from tanh tile (row = lane&15, k-contiguous) ----
    bf16x8 a2[4];
    #pragma unroll
    for (int kk = 0; kk < 4; ++kk)
        a2[kk] = *reinterpret_cast<const bf16x8*>(&Tl[wave][lo][kk * 32 + q * 8]);

    // ---- GEMM2: y = tanh(h) @ W2 ----
    f32x4 acc2[8];
    #pragma unroll
    for (int nb = 0; nb < 8; ++nb) acc2[nb] = f32x4{0.f, 0.f, 0.f, 0.f};
    #pragma unroll
    for (int nb = 0; nb < 8; ++nb) {
        const int col = nb * 16 + lo;
        #pragma unroll
        for (int kk = 0; kk < 4; ++kk) {
            bf16x8 b = *reinterpret_cast<const bf16x8*>(&Wt[col][kk * 32 + q * 8]);
            acc2[nb] = __builtin_amdgcn_mfma_f32_16x16x32_bf16(a2[kk], b, acc2[nb], 0, 0, 0);
        }
    }

    // ---- store (C/D layout: col=nb*16+lo, row=r0+wave*16+q*4+r) ----
    #pragma unroll
    for (int r = 0; r < 4; ++r) {
        int row = r0 + wave * 16 + q * 4 + r;
        if (row < n_rows) {
            #pragma unroll
            for (int nb = 0; nb < 8; ++nb) {
                int c = nb * 16 + lo;
                if (BF16OUT) {
                    dstb[(size_t)row * 128 + c] = f2bf(acc2[nb][r]);
                } else {
                    float* drow = dstf + (size_t)row * 128;
                    if (accumulate) drow[c] += acc2[nb][r];
                    else            drow[c]  = acc2[nb][r];
                }
            }
        }
    }
}

// Merged per-node MLPs -> bf16 tables: blocks [0,nblk) -> FI; [nblk,2*nblk) -> FJ.
__global__ __launch_bounds__(256) void mlp2_kernel(
    const float* __restrict__ src,
    const float* __restrict__ w11, const float* __restrict__ w12,
    const float* __restrict__ w21, const float* __restrict__ w22,
    unsigned short* __restrict__ FI, unsigned short* __restrict__ FJ,
    int n_rows, int nblk)
{
    const bool second = (int)blockIdx.x >= nblk;
    mlp_block<true>(src, nullptr,
                    second ? w21 : w11, second ? w22 : w12,
                    nullptr, second ? FJ : FI, n_rows, 0,
                    second ? (int)blockIdx.x - nblk : (int)blockIdx.x);
}

// Fallback per-edge MLP (workspace too small), fp32 accumulate into out.
__global__ __launch_bounds__(256) void mlp_kernel(
    const float* __restrict__ src, const int* __restrict__ idx,
    const float* __restrict__ W1, const float* __restrict__ W2,
    float* __restrict__ dst, int n_rows, int accumulate)
{
    mlp_block<false>(src, idx, W1, W2, dst, nullptr, n_rows, accumulate,
                     (int)blockIdx.x);
}

// Gather-add: out[e,c] = FI[idx_i[e],c] + FJ[idx_j[e],c].
// Each block owns a CONTIGUOUS 1024-t super-chunk (t = edge*16 + q, 8 bf16
// cols / 32 B output per t), unrolled 4x256: 8 idx loads, then 8 table loads
// in flight per thread, then 4 convert+store groups. Block writes 32 KB
// contiguous; grid-stride keeps the global write stream sequential (R4 law).
__global__ __launch_bounds__(256) void gather_add_kernel(
    const unsigned short* __restrict__ FI, const unsigned short* __restrict__ FJ,
    const int* __restrict__ idx_i, const int* __restrict__ idx_j,
    float* __restrict__ out, int n_edges)
{
    const int total = n_edges * 16;
    const int tid   = threadIdx.x;
    const int gstep = gridDim.x * 1024;

    for (int base = blockIdx.x * 1024; base < total; base += gstep) {
        if (base + 1024 <= total) {
            // full super-chunk: no per-u guards
            int ni[4], nj[4];
            #pragma unroll
            for (int u = 0; u < 4; ++u) {
                const int e = (base + u * 256 + tid) >> 4;
                ni[u] = idx_i[e];
                nj[u] = idx_j[e];
            }
            bf16x8 a[4], b[4];
            #pragma unroll
            for (int u = 0; u < 4; ++u) {
                const int qq = (base + u * 256 + tid) & 15;
                a[u] = *reinterpret_cast<const bf16x8*>(&FI[(size_t)ni[u] * 128 + qq * 8]);
                b[u] = *reinterpret_cast<const bf16x8*>(&FJ[(size_t)nj[u] * 128 + qq * 8]);
            }
            #pragma unroll
            for (int u = 0; u < 4; ++u) {
                const int t = base + u * 256 + tid;
                f32x4 lo, hi;
                #pragma unroll
                for (int k = 0; k < 4; ++k) {
                    lo[k] = bf2f(a[u][k])     + bf2f(b[u][k]);
                    hi[k] = bf2f(a[u][k + 4]) + bf2f(b[u][k + 4]);
                }
                f32x4* op = reinterpret_cast<f32x4*>(&out[(size_t)t * 8]);
                __builtin_nontemporal_store(lo, op);
                __builtin_nontemporal_store(hi, op + 1);
            }
        } else {
            // ragged tail super-chunk
            #pragma unroll
            for (int u = 0; u < 4; ++u) {
                const int t = base + u * 256 + tid;
                if (t < total) {
                    const int e  = t >> 4;
                    const int qq = t & 15;
                    const int ni = idx_i[e];
                    const int nj = idx_j[e];
                    bf16x8 a = *reinterpret_cast<const bf16x8*>(&FI[(size_t)ni * 128 + qq * 8]);
                    bf16x8 b = *reinterpret_cast<const bf16x8*>(&FJ[(size_t)nj * 128 + qq * 8]);
                    f32x4 lo, hi;
                    #pragma unroll
                    for (int k = 0; k < 4; ++k) {
                        lo[k] = bf2f(a[k])     + bf2f(b[k]);
                        hi[k] = bf2f(a[k + 4]) + bf2f(b[k + 4]);
                    }
                    f32x4* op = reinterpret_cast<f32x4*>(&out[(size_t)t * 8]);
                    __builtin_nontemporal_store(lo, op);
                    __builtin_nontemporal_store(hi, op + 1);
                }
            }
        }
    }
}

extern "C" void kernel_launch(void* const* d_in, const int* in_sizes, int n_in,
                              void* d_out, int out_size, void* d_ws, size_t ws_size,
                              hipStream_t stream)
{
    const float* prop  = (const float*)d_in[0];
    const int*   idx_i = (const int*)d_in[1];
    const int*   idx_j = (const int*)d_in[2];
    const float* wi1   = (const float*)d_in[3];
    const float* wi2   = (const float*)d_in[4];
    const float* wj1   = (const float*)d_in[5];
    const float* wj2   = (const float*)d_in[6];
    float* out = (float*)d_out;

    const int n_nodes = in_sizes[0] / 128;
    const int n_edges = in_sizes[1];

    const size_t f_elems = (size_t)n_nodes * 128;
    const size_t need    = 2 * f_elems * sizeof(unsigned short);

    if (ws_size >= need) {
        // Fast path: per-node MLPs into bf16 tables (one dispatch), then gather-add.
        unsigned short* FI = (unsigned short*)d_ws;
        unsigned short* FJ = FI + f_elems;
        int nblk = (n_nodes + 63) / 64;
        mlp2_kernel<<<2 * nblk, 256, 0, stream>>>(prop, wi1, wi2, wj1, wj2,
                                                  FI, FJ, n_nodes, nblk);

        // 2048 blocks = 8 blocks/CU, fully co-resident; contiguous super-chunks.
        gather_add_kernel<<<2048, 256, 0, stream>>>(FI, FJ, idx_i, idx_j,
                                                    out, n_edges);
    } else {
        // Fallback (workspace too small): per-edge MLP with gather, then accumulate pass.
        int nblk = (n_edges + 63) / 64;
        mlp_kernel<<<nblk, 256, 0, stream>>>(prop, idx_i, wi1, wi2, out, n_edges, 0);
        mlp_kernel<<<nblk, 256, 0, stream>>>(prop, idx_j, wj1, wj2, out, n_edges, 1);
    }
}

// Round 10
// 200.254 us; speedup vs baseline: 1.2784x; 1.0319x over previous
//
#include <hip/hip_runtime.h>
#include <hip/hip_bf16.h>

// out[e] = tanh(prop[idx_i[e]] @ wi1) @ wi2 + tanh(prop[idx_j[e]] @ wj1) @ wj2
// Factored: F_I = mlp(prop, wi*), F_J = mlp(prop, wj*)  [per-node, 16x fewer FLOPs]
//           out[e] = F_I[idx_i[e]] + F_J[idx_j[e]]      [gather-add]
//
// FINAL (R9) = R4 structure, the empirical optimum at 202 us.
// Ledger: R4 bf16 flat tables 202 (BEST). R5 L3-phasing 223 (regress).
//   R6 per-XCD L2 shard 247 (regress; broke write-line contiguity).
//   R7 strided 4-unroll 256 (regress; DRAM page thrash).
//   R8 contiguous 8-deep read pipeline 207 (neutral -> NOT latency-bound).
// Structural floor argument: gather moves 826 MB compulsory traffic
//   (410 MB random-256B reads + 410 MB sequential fp32 writes + 6 MB idx)
//   at ~4.6 TB/s combined (~80% of split-stream ideal); reads cannot be
//   cached (memory-side L3 churned by the write stream; 25.6 MB tables >>
//   4 MB per-XCD L2 under random indices), cannot shrink below bf16
//   (fp8 breaches the 4.34e-2 threshold), and cannot be reordered
//   (output edge order is fixed). Five independent attacks confirm.

typedef __attribute__((ext_vector_type(8))) short bf16x8;   // 8 bf16 (4 VGPRs)
typedef __attribute__((ext_vector_type(4))) float f32x4;    // MFMA accumulator / 16B vec

__device__ __forceinline__ unsigned short f2bf(float f) {
    // round-to-nearest-even fp32 -> bf16 (inputs are normal floats)
    unsigned int u = __float_as_uint(f);
    unsigned int r = (u + 0x7fffu + ((u >> 16) & 1u)) >> 16;
    return (unsigned short)r;
}
__device__ __forceinline__ float bf2f(short b) {
    return __uint_as_float((unsigned int)(unsigned short)b << 16);
}

#define LDK 136  // padded LDS row stride in bf16 elems: 272 B (16B-aligned reads)

// Core: tanh(src[map(row)] @ W1) @ W2, 64 rows/block, 4 waves x 16 rows.
// BF16OUT: write bf16 table [row][128]. Else fp32 [row][128] with opt. accumulate.
template <bool BF16OUT>
__device__ __forceinline__ void mlp_block(
    const float* __restrict__ src, const int* __restrict__ idx,
    const float* __restrict__ W1, const float* __restrict__ W2,
    float* __restrict__ dstf, unsigned short* __restrict__ dstb,
    int n_rows, int accumulate, int bid)
{
    __shared__ short Wt[128][LDK];      // W^T as bf16 bits: Wt[n][k] = W[k][n]
    __shared__ short Tl[4][16][LDK];    // per-wave tanh(h) tile (A-operand for GEMM2)

    const int tid  = threadIdx.x;
    const int lane = tid & 63;
    const int wave = tid >> 6;
    const int lo   = lane & 15;   // col within 16-tile / A row
    const int q    = lane >> 4;   // k-group (A/B) / row-group (C/D)
    const int r0   = bid * 64;

    // ---- stage W1^T into LDS (coalesced global read, ds_write_b64) ----
    {
        const int n  = tid & 127;
        const int kq = (tid >> 7) * 4;
        for (int k0 = kq; k0 < 128; k0 += 8) {
            ushort4 p;
            p.x = f2bf(W1[(k0 + 0) * 128 + n]);
            p.y = f2bf(W1[(k0 + 1) * 128 + n]);
            p.z = f2bf(W1[(k0 + 2) * 128 + n]);
            p.w = f2bf(W1[(k0 + 3) * 128 + n]);
            *reinterpret_cast<ushort4*>(&Wt[n][k0]) = p;
        }
    }
    __syncthreads();

    // ---- A fragments: 16 rows per wave, row = lane&15, k = (lane>>4)*8 + i ----
    int arow   = r0 + wave * 16 + lo;
    int arow_c = arow < n_rows ? arow : n_rows - 1;
    int srow   = idx ? idx[arow_c] : arow_c;
    const float4* ap = reinterpret_cast<const float4*>(src + (size_t)srow * 128);

    bf16x8 afr[4];
    #pragma unroll
    for (int kk = 0; kk < 4; ++kk) {
        float4 p0 = ap[kk * 8 + q * 2 + 0];
        float4 p1 = ap[kk * 8 + q * 2 + 1];
        afr[kk][0] = (short)f2bf(p0.x); afr[kk][1] = (short)f2bf(p0.y);
        afr[kk][2] = (short)f2bf(p0.z); afr[kk][3] = (short)f2bf(p0.w);
        afr[kk][4] = (short)f2bf(p1.x); afr[kk][5] = (short)f2bf(p1.y);
        afr[kk][6] = (short)f2bf(p1.z); afr[kk][7] = (short)f2bf(p1.w);
    }

    // ---- GEMM1: h = A @ W1 ----
    f32x4 acc[8];
    #pragma unroll
    for (int nb = 0; nb < 8; ++nb) acc[nb] = f32x4{0.f, 0.f, 0.f, 0.f};
    #pragma unroll
    for (int nb = 0; nb < 8; ++nb) {
        const int col = nb * 16 + lo;
        #pragma unroll
        for (int kk = 0; kk < 4; ++kk) {
            bf16x8 b = *reinterpret_cast<const bf16x8*>(&Wt[col][kk * 32 + q * 8]);
            acc[nb] = __builtin_amdgcn_mfma_f32_16x16x32_bf16(afr[kk], b, acc[nb], 0, 0, 0);
        }
    }

    __syncthreads();  // all waves done reading W1^T before overwrite

    // ---- stage W2^T (reuse Wt) ----
    {
        const int n  = tid & 127;
        const int kq = (tid >> 7) * 4;
        for (int k0 = kq; k0 < 128; k0 += 8) {
            ushort4 p;
            p.x = f2bf(W2[(k0 + 0) * 128 + n]);
            p.y = f2bf(W2[(k0 + 1) * 128 + n]);
            p.z = f2bf(W2[(k0 + 2) * 128 + n]);
            p.w = f2bf(W2[(k0 + 3) * 128 + n]);
            *reinterpret_cast<ushort4*>(&Wt[n][k0]) = p;
        }
    }
    // ---- tanh, C/D layout (col=lane&15, row=(lane>>4)*4+r) -> Tl row-major ----
    #pragma unroll
    for (int nb = 0; nb < 8; ++nb) {
        #pragma unroll
        for (int r = 0; r < 4; ++r) {
            Tl[wave][q * 4 + r][nb * 16 + lo] = (short)f2bf(tanhf(acc[nb][r]));
        }
    }
    __syncthreads();

    // ---- A2 fragments from tanh tile (row = lane&15, k-contiguous) ----
    bf16x8 a2[4];
    #pragma unroll
    for (int kk = 0; kk < 4; ++kk)
        a2[kk] = *reinterpret_cast<const bf16x8*>(&Tl[wave][lo][kk * 32 + q * 8]);

    // ---- GEMM2: y = tanh(h) @ W2 ----
    f32x4 acc2[8];
    #pragma unroll
    for (int nb = 0; nb < 8; ++nb) acc2[nb] = f32x4{0.f, 0.f, 0.f, 0.f};
    #pragma unroll
    for (int nb = 0; nb < 8; ++nb) {
        const int col = nb * 16 + lo;
        #pragma unroll
        for (int kk = 0; kk < 4; ++kk) {
            bf16x8 b = *reinterpret_cast<const bf16x8*>(&Wt[col][kk * 32 + q * 8]);
            acc2[nb] = __builtin_amdgcn_mfma_f32_16x16x32_bf16(a2[kk], b, acc2[nb], 0, 0, 0);
        }
    }

    // ---- store (C/D layout: col=nb*16+lo, row=r0+wave*16+q*4+r) ----
    #pragma unroll
    for (int r = 0; r < 4; ++r) {
        int row = r0 + wave * 16 + q * 4 + r;
        if (row < n_rows) {
            #pragma unroll
            for (int nb = 0; nb < 8; ++nb) {
                int c = nb * 16 + lo;
                if (BF16OUT) {
                    dstb[(size_t)row * 128 + c] = f2bf(acc2[nb][r]);
                } else {
                    float* drow = dstf + (size_t)row * 128;
                    if (accumulate) drow[c] += acc2[nb][r];
                    else            drow[c]  = acc2[nb][r];
                }
            }
        }
    }
}

// Merged per-node MLPs -> bf16 tables: blocks [0,nblk) -> FI; [nblk,2*nblk) -> FJ.
__global__ __launch_bounds__(256) void mlp2_kernel(
    const float* __restrict__ src,
    const float* __restrict__ w11, const float* __restrict__ w12,
    const float* __restrict__ w21, const float* __restrict__ w22,
    unsigned short* __restrict__ FI, unsigned short* __restrict__ FJ,
    int n_rows, int nblk)
{
    const bool second = (int)blockIdx.x >= nblk;
    mlp_block<true>(src, nullptr,
                    second ? w21 : w11, second ? w22 : w12,
                    nullptr, second ? FJ : FI, n_rows, 0,
                    second ? (int)blockIdx.x - nblk : (int)blockIdx.x);
}

// Fallback per-edge MLP (workspace too small), fp32 accumulate into out.
__global__ __launch_bounds__(256) void mlp_kernel(
    const float* __restrict__ src, const int* __restrict__ idx,
    const float* __restrict__ W1, const float* __restrict__ W2,
    float* __restrict__ dst, int n_rows, int accumulate)
{
    mlp_block<false>(src, idx, W1, W2, dst, nullptr, n_rows, accumulate,
                     (int)blockIdx.x);
}

// out[e] = FI[idx_i[e]] + FJ[idx_j[e]] with bf16 tables.
// 16 lanes per edge; each lane: 2x 16B bf16x8 load, convert+add, 32B fp32 NT
// store. Per wave: 4 edges, 2 KB of contiguous sequential output per 64 lanes
// (the write stream stays line-perfect -- the 3x-confirmed law).
__global__ __launch_bounds__(256) void gather_add_kernel(
    const bf16x8* __restrict__ FI, const bf16x8* __restrict__ FJ,
    const int* __restrict__ idx_i, const int* __restrict__ idx_j,
    f32x4* __restrict__ out, int n_edges)
{
    const int total = n_edges * 16;  // 16 bf16x8 chunks per 128-elem row
    for (int t = blockIdx.x * 256 + threadIdx.x; t < total; t += gridDim.x * 256) {
        int e  = t >> 4;
        int qq = t & 15;
        int ni = idx_i[e];
        int nj = idx_j[e];
        bf16x8 a = FI[(size_t)ni * 16 + qq];
        bf16x8 b = FJ[(size_t)nj * 16 + qq];
        f32x4 lo, hi;
        #pragma unroll
        for (int k = 0; k < 4; ++k) {
            lo[k] = bf2f(a[k])     + bf2f(b[k]);
            hi[k] = bf2f(a[k + 4]) + bf2f(b[k + 4]);
        }
        __builtin_nontemporal_store(lo, &out[(size_t)t * 2 + 0]);  // write-once stream
        __builtin_nontemporal_store(hi, &out[(size_t)t * 2 + 1]);
    }
}

extern "C" void kernel_launch(void* const* d_in, const int* in_sizes, int n_in,
                              void* d_out, int out_size, void* d_ws, size_t ws_size,
                              hipStream_t stream)
{
    const float* prop  = (const float*)d_in[0];
    const int*   idx_i = (const int*)d_in[1];
    const int*   idx_j = (const int*)d_in[2];
    const float* wi1   = (const float*)d_in[3];
    const float* wi2   = (const float*)d_in[4];
    const float* wj1   = (const float*)d_in[5];
    const float* wj2   = (const float*)d_in[6];
    float* out = (float*)d_out;

    const int n_nodes = in_sizes[0] / 128;
    const int n_edges = in_sizes[1];

    const size_t f_elems = (size_t)n_nodes * 128;
    const size_t need    = 2 * f_elems * sizeof(unsigned short);

    if (ws_size >= need) {
        // Fast path: per-node MLPs into bf16 tables (one dispatch), then gather-add.
        unsigned short* FI = (unsigned short*)d_ws;
        unsigned short* FJ = FI + f_elems;
        int nblk = (n_nodes + 63) / 64;
        mlp2_kernel<<<2 * nblk, 256, 0, stream>>>(prop, wi1, wi2, wj1, wj2,
                                                  FI, FJ, n_nodes, nblk);

        int total  = n_edges * 16;
        int blocks = (total + 255) / 256;
        if (blocks > 2048) blocks = 2048;
        gather_add_kernel<<<blocks, 256, 0, stream>>>(
            (const bf16x8*)FI, (const bf16x8*)FJ, idx_i, idx_j,
            (f32x4*)out, n_edges);
    } else {
        // Fallback (workspace too small): per-edge MLP with gather, then accumulate pass.
        int nblk = (n_edges + 63) / 64;
        mlp_kernel<<<nblk, 256, 0, stream>>>(prop, idx_i, wi1, wi2, out, n_edges, 0);
        mlp_kernel<<<nblk, 256, 0, stream>>>(prop, idx_j, wj1, wj2, out, n_edges, 1);
    }
}